// Round 8
// baseline (184.651 us; speedup 1.0000x reference)
//
#include <hip/hip_runtime.h>
#include <math.h>

// CrossDomainBridge — MI355X split-bf16 MFMA mega-kernel (round 17).
//
// Math shortcut (exact): softmax rows sum to 1 => corr == 1/2048, dw == 1/8,
// corr_mean == 1/2048; gate bias folds: bg_eff = bg + (1/2048)*sum(Wg[128:131]).
//
// Round-16 post-mortem: x-direct regressed (73.4->80.5us) — killed the
// 8-wave sharing of the x conversion; reverted to r15 structure. New
// theory: the per-CU LDS pipe is the hidden near-critical resource —
// ~500 ds_read_b128/CU/phase + scalar b16 column-scatter tail writes at
// 4-way bank conflict (3.87M conflict cycles ~ 8.5% wall, plus 2x the
// needed write transactions). THIS ROUND (r15 + LDS-traffic cuts):
//   1) shuffle-pack tails: lanes 2k/2k+1 hold adjacent cols of one row;
//      shfl_xor(1) then even lanes write hi plane, odd lanes lo plane,
//      single b32 each — half the transactions;
//   2) lo planes offset +8 dwords (tl/al/el = hi + 32*P + 16) so hi/lo
//      writes in one instruction hit disjoint bank octets (<=2-way=free);
//   3) enh phase reconstructs t from live tac regs — deletes 16 u16
//      conflicted LDS reads/lane;
//   4) ostage pitch 128->132 (f32 LN writes were 4-way).
// Barrier schedule/count = r15 (lgkm-only ldsbar, 18 intervals).
// Weights pre-packed in d_ws (needs >= 655360 B).
//
// d_out layout (floats): out[2097152] corr[72] dw[24] enh0 enh1 enh2

typedef __attribute__((ext_vector_type(8))) short short8;
typedef __attribute__((ext_vector_type(4))) float f32x4;
#define MFMA(a, b, c) __builtin_amdgcn_mfma_f32_16x16x32_bf16(a, b, c, 0, 0, 0)

#define NTOK 32
#define XP 72      // x plane pitch (shorts)
#define AP 264     // a plane pitch (shorts)
#define TP 136     // t/enh/fused plane pitch (shorts)
#define PP 12      // psum row pitch (floats)
#define OP 132     // ostage pitch (floats)
#define PLPAD 16   // hi->lo plane extra offset (shorts) = 8 dwords

// ws layout (elems, bf16): each matrix [hi S][lo S]
#define WD0_B 0u
#define WD1_B 32768u
#define WD2_B 65536u
#define WT_B  98304u
#define WG_B  163840u
#define WF0_B 196608u
#define WF1_B 229376u
#define WF2_B 262144u
#define WDF_B 294912u

__device__ __forceinline__ unsigned short bf16rtn(float v) {
    unsigned u = __float_as_uint(v);
    unsigned r = u + 0x7FFFu + ((u >> 16) & 1u);
    return (unsigned short)(r >> 16);
}
__device__ __forceinline__ void split2(float v, unsigned short& h, unsigned short& l) {
    h = bf16rtn(v);
    float hf = __uint_as_float(((unsigned)h) << 16);
    l = bf16rtn(v - hf);
}
__device__ __forceinline__ float bf2f(unsigned short h) {
    return __uint_as_float(((unsigned)h) << 16);
}

// LDS-only barrier: order ds ops (lgkmcnt(0)) but let global loads/stores
// stay in flight across the barrier. sched_barrier(0) fences both sides
// against compiler reordering (rule #18).
__device__ __forceinline__ void ldsbar() {
    asm volatile("s_waitcnt lgkmcnt(0)" ::: "memory");
    __builtin_amdgcn_sched_barrier(0);
    __builtin_amdgcn_s_barrier();
    __builtin_amdgcn_sched_barrier(0);
    asm volatile("" ::: "memory");
}

// Packed RTNE bf16 pair: lo16 = bf16(a), hi16 = bf16(b).
__device__ __forceinline__ unsigned cvt_pk_bf16(float a, float b) {
    unsigned r;
    asm("v_cvt_pk_bf16_f32 %0, %1, %2" : "=v"(r) : "v"(a), "v"(b));
    return r;
}
// Split two floats into packed-hi and packed-lo bf16 pairs (RTNE, identical
// numerics to split2 on both elements).
__device__ __forceinline__ void split2pk(float a, float b, unsigned& hp, unsigned& lp) {
    hp = cvt_pk_bf16(a, b);
    const float ha = __uint_as_float(hp << 16);
    const float hb = __uint_as_float(hp & 0xffff0000u);
    lp = cvt_pk_bf16(a - ha, b - hb);
}

// Column-pair packed plane write: this lane holds value v at column
// (colbase + lm); its lane^1 neighbor holds the adjacent column of the
// SAME row. Even-lm lanes write the hi plane b32 (cols cb, cb+1), odd-lm
// lanes write the lo plane b32. idx = row*pitch + (col & ~1). With the lo
// plane offset +8 dwords, the single ds_write_b32 hits disjoint bank
// octets for even/odd lanes (<=2-way, free).
__device__ __forceinline__ void packwr(unsigned short* __restrict__ hi,
                                       unsigned short* __restrict__ lo,
                                       int idx, int odd, float v) {
    const float vn = __shfl_xor(v, 1);
    const float a = odd ? vn : v;
    const float b = odd ? v : vn;
    unsigned hp, lp;
    split2pk(a, b, hp, lp);
    unsigned short* p = odd ? lo : hi;
    *(unsigned*)&p[idx] = odd ? lp : hp;
}

// Stage one f32x4 of x into the split planes (8B stores).
__device__ __forceinline__ void stage_x(const f32x4 v,
                                        unsigned short* __restrict__ xh,
                                        unsigned short* __restrict__ xl,
                                        int stok, int sc4) {
    unsigned h01, l01, h23, l23;
    split2pk(v.x, v.y, h01, l01);
    split2pk(v.z, v.w, h23, l23);
    *(uint2*)&xh[stok * XP + sc4] = make_uint2(h01, h23);
    *(uint2*)&xl[stok * XP + sc4] = make_uint2(l01, l23);
}

// Pack weights into fragment-linear split-bf16: for matrix W[K][N], frag
// (nt,kc): lane holds W[kc*32+(lane>>4)*8 + j][nt*16+(lane&15)], j=0..7.
__global__ __launch_bounds__(256) void prep_kernel(
    const float* __restrict__ Ws, const float* __restrict__ Wf,
    const float* __restrict__ Ww, const float* __restrict__ Wt,
    const float* __restrict__ Wg, const float* __restrict__ Wfu,
    const float* __restrict__ Wdf, unsigned short* __restrict__ ws)
{
    int s = blockIdx.x * 256 + threadIdx.x;   // 0..20479 frag-lane slots
    const float* src; int K, N; unsigned base, S; int fi;
    if (s < 2048)      { src = Ws;            K = 64;  N = 256; base = WD0_B; S = 16384; fi = s; }
    else if (s < 4096) { src = Wf;            K = 64;  N = 256; base = WD1_B; S = 16384; fi = s - 2048; }
    else if (s < 6144) { src = Ww;            K = 64;  N = 256; base = WD2_B; S = 16384; fi = s - 4096; }
    else if (s < 10240){ src = Wt;            K = 256; N = 128; base = WT_B;  S = 32768; fi = s - 6144; }
    else if (s < 12288){ src = Wg;            K = 128; N = 128; base = WG_B;  S = 16384; fi = s - 10240; }
    else if (s < 14336){ src = Wfu;           K = 128; N = 128; base = WF0_B; S = 16384; fi = s - 12288; }
    else if (s < 16384){ src = Wfu + 16384;   K = 128; N = 128; base = WF1_B; S = 16384; fi = s - 14336; }
    else if (s < 18432){ src = Wfu + 32768;   K = 128; N = 128; base = WF2_B; S = 16384; fi = s - 16384; }
    else               { src = Wdf;           K = 128; N = 128; base = WDF_B; S = 16384; fi = s - 18432; }
    const int lane = fi & 63, frag = fi >> 6;
    const int KC = K >> 5;
    const int nt = frag / KC, kc = frag - nt * KC;
    const int n  = nt * 16 + (lane & 15);
    const int k0 = kc * 32 + (lane >> 4) * 8;
    short8 hv, lv;
    #pragma unroll
    for (int j = 0; j < 8; ++j) {
        unsigned short h, l;
        split2(src[(k0 + j) * N + n], h, l);
        hv[j] = (short)h; lv[j] = (short)l;
    }
    *(short8*)&ws[base + (unsigned)fi * 8]     = hv;
    *(short8*)&ws[base + S + (unsigned)fi * 8] = lv;
}

// K=128 phase: acc[2] over both m-tiles, ALL 4 B pairs loaded upfront
// (full-depth prefetch). A planes at TP pitch. m-tile chains interleaved.
__device__ __forceinline__ void gemm128_d2(
    const unsigned short* __restrict__ wsB, unsigned S,
    const unsigned short* __restrict__ Ph, const unsigned short* __restrict__ Pl,
    int tok0, int tok1, int quad, int wv, int lane, f32x4 acc[2])
{
    short8 Bh[4], Bl[4];
    #pragma unroll
    for (int j = 0; j < 4; ++j) {
        const unsigned short* bp = wsB + ((unsigned)(wv * 4 + j) * 64 + lane) * 8;
        Bh[j] = *(const short8*)bp; Bl[j] = *(const short8*)(bp + S);
    }
    #pragma unroll
    for (int kc = 0; kc < 4; ++kc) {
        const int k = kc * 32 + quad * 8;
        const short8 Ah0 = *(const short8*)&Ph[tok0 * TP + k];
        const short8 Al0 = *(const short8*)&Pl[tok0 * TP + k];
        const short8 Ah1 = *(const short8*)&Ph[tok1 * TP + k];
        const short8 Al1 = *(const short8*)&Pl[tok1 * TP + k];
        acc[0] = MFMA(Ah0, Bh[kc], acc[0]);
        acc[1] = MFMA(Ah1, Bh[kc], acc[1]);
        acc[0] = MFMA(Al0, Bh[kc], acc[0]);
        acc[1] = MFMA(Al1, Bh[kc], acc[1]);
        acc[0] = MFMA(Ah0, Bl[kc], acc[0]);
        acc[1] = MFMA(Ah1, Bl[kc], acc[1]);
    }
}

__global__ __launch_bounds__(512) void mega_kernel(
    const float* __restrict__ x0, const float* __restrict__ x1,
    const float* __restrict__ x2,
    const float* __restrict__ bd0, const float* __restrict__ bd1,
    const float* __restrict__ bd2,
    const float* __restrict__ g1, const float* __restrict__ b1,
    const float* __restrict__ bt, const float* __restrict__ Wg,
    const float* __restrict__ bg, const float* __restrict__ bfu,
    const float* __restrict__ bdf, const float* __restrict__ g2,
    const float* __restrict__ b2,
    const unsigned short* __restrict__ ws,
    float* __restrict__ out, float* __restrict__ consts,
    float* __restrict__ e0, float* __restrict__ e1, float* __restrict__ e2)
{
    // 54400 B carve with aliasing (2 blocks/CU):
    //   [0,17472):      xh/xl[32*72] UNION {th [32][TP], pad 16, tl [32][TP]}
    //   [17472,51328):  {ah [32][AP], pad 16, al} UNION {eh, pad, el} UNION ostage[32][OP]
    //   [51328,54400):  psumS[32][PP], psumQ[32][PP]
    __shared__ __align__(16) unsigned char smem[54400];
    unsigned short* xh = (unsigned short*)smem;            // [32][XP]
    unsigned short* xl = xh + 32 * XP;
    unsigned short* th = (unsigned short*)smem;            // [32][TP]
    unsigned short* tl = th + 32 * TP + PLPAD;             // +8 dwords: bank-disjoint
    unsigned short* ah = (unsigned short*)(smem + 17472);  // [32][AP]
    unsigned short* al = ah + 32 * AP + PLPAD;
    unsigned short* eh = (unsigned short*)(smem + 17472);  // [32][TP] enh planes
    unsigned short* el = eh + 32 * TP + PLPAD;
    float* ostage = (float*)(smem + 17472);                // [32][OP], aliases ah/eh
    float* psumS  = (float*)(smem + 51328);                // [32][PP]
    float* psumQ  = psumS + 32 * PP;                       // [32][PP]

    const int tid = threadIdx.x, wv = tid >> 6, lane = tid & 63;
    const int lm = lane & 15, quad = lane >> 4;
    const int odd = lm & 1;
    const int row0 = blockIdx.x * NTOK;
    const int tok0 = lm, tok1 = lm + 16;
    const int stok = tid >> 4, sc4 = (tid & 15) * 4;   // x-staging coords

    if (blockIdx.x == 0) {
        if (tid < 72) consts[tid] = 4.8828125e-4f;      // corr = 1/2048
        else if (tid < 96) consts[tid] = 0.125f;        // dw = 1/8
    }

    // columns: phase A -> 2 ntiles/wave (32 cols); 128-col phases -> 1 ntile
    int cA[2]; float g1c[2], b1c[2];
    #pragma unroll
    for (int i = 0; i < 2; ++i) { cA[i] = (wv * 2 + i) * 16 + lm; g1c[i] = g1[cA[i]]; b1c[i] = b1[cA[i]]; }
    const int cA0e = cA[0] & ~1, cA1e = cA[1] & ~1;
    const int cT = wv * 16 + lm;
    const int cTe = cT & ~1;
    const float btc = bt[cT];
    const float bgc = bg[cT] + 4.8828125e-4f * (Wg[16384 + cT] + Wg[16512 + cT] + Wg[16640 + cT]);
    const float bdc = bdf[cT], g2c = g2[cT], b2c = b2[cT];
    f32x4 facc[2];
    { const float bv = bfu[cT]; facc[0] = (f32x4){bv, bv, bv, bv}; facc[1] = facc[0]; }

    const float* xs[3]  = {x0, x1, x2};
    const float* bds[3] = {bd0, bd1, bd2};
    float* es[3] = {e0, e1, e2};
    const unsigned WDB[3] = {WD0_B, WD1_B, WD2_B};
    const unsigned WFB[3] = {WF0_B, WF1_B, WF2_B};

    // ---- pre-loop: stage x for d=0 ----
    {
        const f32x4 v = __builtin_nontemporal_load(
            (const f32x4*)&xs[0][(row0 + stok) * 64 + sc4]);
        stage_x(v, xh, xl, stok, sc4);
    }
    ldsbar();                               // B_a: x(0) planes ready

    for (int d = 0; d < 3; ++d) {
        // ---- Phase A: a_raw = x @ Wd + bd. 2 ntiles x 2 m, all-4 B upfront ----
        f32x4 acc[2][2];                    // [ntile i][mtile m]
        {
            const float* bdp = bds[d];
            #pragma unroll
            for (int i = 0; i < 2; ++i) {
                const float bv = bdp[cA[i]];
                acc[i][0] = (f32x4){bv, bv, bv, bv}; acc[i][1] = acc[i][0];
            }
        }
        {
            short8 Bh[4], Bl[4];            // f = kc*2 + i; frag = (wv*2+i)*2+kc
            #pragma unroll
            for (int f = 0; f < 4; ++f) {
                const int kc = f >> 1, i = f & 1;
                const unsigned short* bp = ws + WDB[d] +
                    ((unsigned)((wv * 2 + i) * 2 + kc) * 64 + lane) * 8;
                Bh[f] = *(const short8*)bp; Bl[f] = *(const short8*)(bp + 16384);
            }
            #pragma unroll
            for (int f = 0; f < 4; ++f) {   // f = kc*2 + i
                const int kc = f >> 1, i = f & 1;
                const int k = kc * 32 + quad * 8;
                const short8 Ah0 = *(const short8*)&xh[tok0 * XP + k];
                const short8 Al0 = *(const short8*)&xl[tok0 * XP + k];
                const short8 Ah1 = *(const short8*)&xh[tok1 * XP + k];
                const short8 Al1 = *(const short8*)&xl[tok1 * XP + k];
                acc[i][0] = MFMA(Ah0, Bh[f], acc[i][0]);
                acc[i][1] = MFMA(Ah1, Bh[f], acc[i][1]);
                acc[i][0] = MFMA(Al0, Bh[f], acc[i][0]);
                acc[i][1] = MFMA(Al1, Bh[f], acc[i][1]);
                acc[i][0] = MFMA(Ah0, Bl[f], acc[i][0]);
                acc[i][1] = MFMA(Ah1, Bl[f], acc[i][1]);
            }
        }
        // LN partials over this wave's 32 cols
        #pragma unroll
        for (int m = 0; m < 2; ++m)
            #pragma unroll
            for (int r = 0; r < 4; ++r) {
                float s = acc[0][m][r] + acc[1][m][r];
                float q = acc[0][m][r] * acc[0][m][r] + acc[1][m][r] * acc[1][m][r];
                #pragma unroll
                for (int off = 1; off < 16; off <<= 1) {
                    s += __shfl_xor(s, off); q += __shfl_xor(q, off);
                }
                if (lm == 0) {
                    const int row = m * 16 + quad * 4 + r;
                    psumS[row * PP + wv] = s;
                    psumQ[row * PP + wv] = q;
                }
            }
        ldsbar();                           // B_b: psum ready (also: all x reads done)

        // normalize + a-planes store (shuffle-packed b32, bank-disjoint)
        #pragma unroll
        for (int m = 0; m < 2; ++m)
            #pragma unroll
            for (int r = 0; r < 4; ++r) {
                const int row = m * 16 + quad * 4 + r;
                const float4 s0 = *(const float4*)&psumS[row * PP];
                const float4 s1 = *(const float4*)&psumS[row * PP + 4];
                const float4 q0 = *(const float4*)&psumQ[row * PP];
                const float4 q1 = *(const float4*)&psumQ[row * PP + 4];
                const float S = s0.x + s0.y + s0.z + s0.w + s1.x + s1.y + s1.z + s1.w;
                const float Q = q0.x + q0.y + q0.z + q0.w + q1.x + q1.y + q1.z + q1.w;
                const float mean = S * (1.f / 256.f);
                const float rs = rsqrtf(Q * (1.f / 256.f) - mean * mean + 1e-3f);
                const float v0 = (acc[0][m][r] - mean) * rs * g1c[0] + b1c[0];
                const float v1 = (acc[1][m][r] - mean) * rs * g1c[1] + b1c[1];
                packwr(ah, al, row * AP + cA0e, odd, v0);
                packwr(ah, al, row * AP + cA1e, odd, v1);
            }
        ldsbar();                           // B_c: a planes ready

        // prefetch next domain's x into regs (used at tail — latency hidden;
        // stays in flight across B_d/B_e with lgkm-only barriers)
        f32x4 xvn;
        if (d < 2)
            xvn = __builtin_nontemporal_load(
                (const f32x4*)&xs[d + 1][(row0 + stok) * 64 + sc4]);

        // ---- Phase T: t = a @ Wt + bt. 8 kc, depth-4 B roll ----
        f32x4 tac[2];
        tac[0] = (f32x4){btc, btc, btc, btc}; tac[1] = tac[0];
        {
            short8 Bh[4], Bl[4];
            #pragma unroll
            for (int j = 0; j < 4; ++j) {
                const unsigned short* bp = ws + WT_B + ((unsigned)(wv * 8 + j) * 64 + lane) * 8;
                Bh[j] = *(const short8*)bp; Bl[j] = *(const short8*)(bp + 32768);
            }
            #pragma unroll
            for (int kc = 0; kc < 8; ++kc) {
                const short8 bh = Bh[kc & 3], bl = Bl[kc & 3];
                if (kc + 4 < 8) {
                    const unsigned short* bp = ws + WT_B + ((unsigned)(wv * 8 + kc + 4) * 64 + lane) * 8;
                    Bh[kc & 3] = *(const short8*)bp; Bl[kc & 3] = *(const short8*)(bp + 32768);
                }
                const int k = kc * 32 + quad * 8;
                const short8 Ah0 = *(const short8*)&ah[tok0 * AP + k];
                const short8 Al0 = *(const short8*)&al[tok0 * AP + k];
                const short8 Ah1 = *(const short8*)&ah[tok1 * AP + k];
                const short8 Al1 = *(const short8*)&al[tok1 * AP + k];
                tac[0] = MFMA(Ah0, bh, tac[0]);
                tac[1] = MFMA(Ah1, bh, tac[1]);
                tac[0] = MFMA(Al0, bh, tac[0]);
                tac[1] = MFMA(Al1, bh, tac[1]);
                tac[0] = MFMA(Ah0, bl, tac[0]);
                tac[1] = MFMA(Ah1, bl, tac[1]);
            }
        }
        // t -> th/tl (shuffle-packed b32; x region free after B_b)
        #pragma unroll
        for (int m = 0; m < 2; ++m) {
            const int rb = m * 16 + quad * 4;
            #pragma unroll
            for (int r = 0; r < 4; ++r)
                packwr(th, tl, (rb + r) * TP + cTe, odd, tac[m][r]);
        }
        ldsbar();                           // B_d: t planes ready (also: all a reads done)

        // ---- Phase G: z = t @ Wg0 + bg_eff ----
        f32x4 zac[2];
        zac[0] = (f32x4){bgc, bgc, bgc, bgc}; zac[1] = zac[0];
        gemm128_d2(ws + WG_B, 16384, th, tl, tok0, tok1, quad, wv, lane, zac);

        // enh = t * sigmoid(z)/8 -> eh/el. t reconstructed from LIVE tac
        // regs (no LDS read-back): tv = hi(t)+lo(t) rounding, identical to
        // what the planes hold.
        #pragma unroll
        for (int m = 0; m < 2; ++m) {
            const int rb = m * 16 + quad * 4;
            #pragma unroll
            for (int r = 0; r < 4; ++r) {
                unsigned short h, l; split2(tac[m][r], h, l);
                const float tv = bf2f(h) + bf2f(l);
                const float e = tv * (1.f / (1.f + __expf(-zac[m][r]))) * 0.125f;
                packwr(eh, el, (rb + r) * TP + cTe, odd, e);
            }
        }
        ldsbar();                           // B_e: enh planes ready (also: all t/G reads done)

        // ---- Fuse acc: facc += enh_d @ Wfu_d (reads eh/el) ----
        gemm128_d2(ws + WFB[d], 16384, eh, el, tok0, tok1, quad, wv, lane, facc);

        // enh global store: full 512B rows, nontemporal (ack never waited)
        #pragma unroll
        for (int p = 0; p < 2; ++p) {
            const int row = (tid >> 5) + p * 16;
            const int c4 = (tid & 31) * 4;
            const ushort4 h0 = *(const ushort4*)&eh[row * TP + c4];
            const ushort4 l0 = *(const ushort4*)&el[row * TP + c4];
            f32x4 o = {bf2f(h0.x) + bf2f(l0.x), bf2f(h0.y) + bf2f(l0.y),
                       bf2f(h0.z) + bf2f(l0.z), bf2f(h0.w) + bf2f(l0.w)};
            __builtin_nontemporal_store(o, (f32x4*)(es[d] + (row0 + row) * 128 + c4));
        }

        // tail store into th/tl or x planes (region free after B_e)
        if (d < 2) {
            stage_x(xvn, xh, xl, stok, sc4);
        } else {
            #pragma unroll
            for (int m = 0; m < 2; ++m) {
                const int rb = m * 16 + quad * 4;
                #pragma unroll
                for (int r = 0; r < 4; ++r)
                    packwr(th, tl, (rb + r) * TP + cTe, odd, facc[m][r]);
            }
        }
        ldsbar();                           // B_f: region ready for next phase
    }

    // ---- df = fused @ Wdf + bdf (reads th/tl) ----
    f32x4 dac[2];
    dac[0] = (f32x4){bdc, bdc, bdc, bdc}; dac[1] = dac[0];
    gemm128_d2(ws + WDF_B, 16384, th, tl, tok0, tok1, quad, wv, lane, dac);

    // ---- final LN over 128 (wave partial = its 16 cols) ----
    #pragma unroll
    for (int m = 0; m < 2; ++m)
        #pragma unroll
        for (int r = 0; r < 4; ++r) {
            float s = dac[m][r];
            float q = dac[m][r] * dac[m][r];
            #pragma unroll
            for (int off = 1; off < 16; off <<= 1) {
                s += __shfl_xor(s, off); q += __shfl_xor(q, off);
            }
            if (lm == 0) {
                const int row = m * 16 + quad * 4 + r;
                psumS[row * PP + wv] = s;
                psumQ[row * PP + wv] = q;
            }
        }
    ldsbar();
    #pragma unroll
    for (int m = 0; m < 2; ++m)
        #pragma unroll
        for (int r = 0; r < 4; ++r) {
            const int row = m * 16 + quad * 4 + r;
            const float4 s0 = *(const float4*)&psumS[row * PP];
            const float4 s1 = *(const float4*)&psumS[row * PP + 4];
            const float4 q0 = *(const float4*)&psumQ[row * PP];
            const float4 q1 = *(const float4*)&psumQ[row * PP + 4];
            const float S = s0.x + s0.y + s0.z + s0.w + s1.x + s1.y + s1.z + s1.w;
            const float Q = q0.x + q0.y + q0.z + q0.w + q1.x + q1.y + q1.z + q1.w;
            const float mean = S * (1.f / 128.f);
            const float rs = rsqrtf(Q * (1.f / 128.f) - mean * mean + 1e-3f);
            ostage[row * OP + cT] = (dac[m][r] - mean) * rs * g2c + b2c;
        }
    ldsbar();
    // out store: full lines
    #pragma unroll
    for (int p = 0; p < 2; ++p) {
        const int row = (tid >> 5) + p * 16;
        const int c4 = (tid & 31) * 4;
        const f32x4 o = *(const f32x4*)&ostage[row * OP + c4];
        __builtin_nontemporal_store(o, (f32x4*)(out + (row0 + row) * 128 + c4));
    }
}

extern "C" void kernel_launch(void* const* d_in, const int* in_sizes, int n_in,
                              void* d_out, int out_size, void* d_ws, size_t ws_size,
                              hipStream_t stream) {
    const float* spatial   = (const float*)d_in[0];
    const float* frequency = (const float*)d_in[1];
    const float* wavelet   = (const float*)d_in[2];
    const float* Ws  = (const float*)d_in[3];
    const float* bs  = (const float*)d_in[4];
    const float* Wf  = (const float*)d_in[5];
    const float* bf  = (const float*)d_in[6];
    const float* Ww  = (const float*)d_in[7];
    const float* bw  = (const float*)d_in[8];
    const float* g1  = (const float*)d_in[9];
    const float* b1  = (const float*)d_in[10];
    // d_in[11..14] = Wk, bk, Wq, bq — provably unused (corr is constant)
    const float* Wt  = (const float*)d_in[15];
    const float* bt  = (const float*)d_in[16];
    const float* Wg  = (const float*)d_in[17];
    const float* bg  = (const float*)d_in[18];
    const float* Wfu = (const float*)d_in[19];
    const float* bfu = (const float*)d_in[20];
    const float* Wdf = (const float*)d_in[21];
    const float* bdf = (const float*)d_in[22];
    const float* g2  = (const float*)d_in[23];
    const float* b2  = (const float*)d_in[24];

    float* out    = (float*)d_out;
    float* consts = out + 2097152;          // corr[72] + dw[24]
    float* enh0   = out + 2097248;
    float* enh1   = out + 4194400;
    float* enh2   = out + 6291552;
    unsigned short* wsp = (unsigned short*)d_ws;   // needs 655360 B

    prep_kernel<<<80, 256, 0, stream>>>(Ws, Wf, Ww, Wt, Wg, Wfu, Wdf, wsp);
    mega_kernel<<<16384 / NTOK, 512, 0, stream>>>(
        spatial, frequency, wavelet, bs, bf, bw, g1, b1,
        bt, Wg, bg, bfu, bdf, g2, b2, wsp,
        out, consts, enh0, enh1, enh2);
}

// Round 9
// 174.904 us; speedup vs baseline: 1.0557x; 1.0557x over previous
//
#include <hip/hip_runtime.h>
#include <math.h>

// CrossDomainBridge — MI355X split-bf16 MFMA mega-kernel (round 18).
//
// Math shortcut (exact): softmax rows sum to 1 => corr == 1/2048, dw == 1/8,
// corr_mean == 1/2048; gate bias folds: bg_eff = bg + (1/2048)*sum(Wg[128:131]).
//
// Round-17 post-mortem: packwr regressed (73.4->79.2us) — __shfl_xor IS an
// LDS-pipe op (ds_bpermute); added traffic instead of cutting it (VALU
// 26->31.5, conflicts unchanged). Full revert to r15. Surviving signal:
// MfmaUtil 13.6% x 176K cyc / 1536 MFMA = ~16 cyc/MFMA = dependent-issue
// latency (vs ~5 throughput) — the split triple is a 3-chain on one acc,
// and 2 interleaved m-tiles give distance 2 (~10cyc) < 16cyc latency.
// THIS ROUND (one variable): 3 independent chains per m-tile accumulator
// (hi=Ah*Bh, la=Al*Bh, lb=Ah*Bl; two exact f32 adds at phase end) in
// gemm128 + T phase -> 6 chains, distance 6 (~30cyc) > latency -> MFMA
// issue fully pipelined. Reassociation noise ~2^-24, budget 2^-10. +16
// VGPR transient (watch >128).
// Barrier schedule = r15 (lgkm-only ldsbar, 18 intervals).
// Weights pre-packed in d_ws (needs >= 655360 B).
//
// d_out layout (floats): out[2097152] corr[72] dw[24] enh0 enh1 enh2

typedef __attribute__((ext_vector_type(8))) short short8;
typedef __attribute__((ext_vector_type(4))) float f32x4;
#define MFMA(a, b, c) __builtin_amdgcn_mfma_f32_16x16x32_bf16(a, b, c, 0, 0, 0)

#define NTOK 32
#define XP 72      // x plane pitch (shorts): 16B-aligned rows
#define AP 264     // a plane pitch
#define TP 136     // t/enh/fused plane pitch
#define PP 12      // psum row pitch (floats): 48B, float4-aligned, quad-spread

// ws layout (elems, bf16): each matrix [hi S][lo S]
#define WD0_B 0u
#define WD1_B 32768u
#define WD2_B 65536u
#define WT_B  98304u
#define WG_B  163840u
#define WF0_B 196608u
#define WF1_B 229376u
#define WF2_B 262144u
#define WDF_B 294912u

__device__ __forceinline__ unsigned short bf16rtn(float v) {
    unsigned u = __float_as_uint(v);
    unsigned r = u + 0x7FFFu + ((u >> 16) & 1u);
    return (unsigned short)(r >> 16);
}
__device__ __forceinline__ void split2(float v, unsigned short& h, unsigned short& l) {
    h = bf16rtn(v);
    float hf = __uint_as_float(((unsigned)h) << 16);
    l = bf16rtn(v - hf);
}
__device__ __forceinline__ float bf2f(unsigned short h) {
    return __uint_as_float(((unsigned)h) << 16);
}

// LDS-only barrier: order ds ops (lgkmcnt(0)) but let global loads/stores
// stay in flight across the barrier. sched_barrier(0) fences both sides
// against compiler reordering (rule #18).
__device__ __forceinline__ void ldsbar() {
    asm volatile("s_waitcnt lgkmcnt(0)" ::: "memory");
    __builtin_amdgcn_sched_barrier(0);
    __builtin_amdgcn_s_barrier();
    __builtin_amdgcn_sched_barrier(0);
    asm volatile("" ::: "memory");
}

// Packed RTNE bf16 pair: lo16 = bf16(a), hi16 = bf16(b).
__device__ __forceinline__ unsigned cvt_pk_bf16(float a, float b) {
    unsigned r;
    asm("v_cvt_pk_bf16_f32 %0, %1, %2" : "=v"(r) : "v"(a), "v"(b));
    return r;
}
// Split two floats into packed-hi and packed-lo bf16 pairs (RTNE, identical
// numerics to split2 on both elements).
__device__ __forceinline__ void split2pk(float a, float b, unsigned& hp, unsigned& lp) {
    hp = cvt_pk_bf16(a, b);
    const float ha = __uint_as_float(hp << 16);
    const float hb = __uint_as_float(hp & 0xffff0000u);
    lp = cvt_pk_bf16(a - ha, b - hb);
}
// Stage one f32x4 of x into the split planes (8B stores).
__device__ __forceinline__ void stage_x(const f32x4 v,
                                        unsigned short* __restrict__ xh,
                                        unsigned short* __restrict__ xl,
                                        int stok, int sc4) {
    unsigned h01, l01, h23, l23;
    split2pk(v.x, v.y, h01, l01);
    split2pk(v.z, v.w, h23, l23);
    *(uint2*)&xh[stok * XP + sc4] = make_uint2(h01, h23);
    *(uint2*)&xl[stok * XP + sc4] = make_uint2(l01, l23);
}

// Pack weights into fragment-linear split-bf16: for matrix W[K][N], frag
// (nt,kc): lane holds W[kc*32+(lane>>4)*8 + j][nt*16+(lane&15)], j=0..7.
__global__ __launch_bounds__(256) void prep_kernel(
    const float* __restrict__ Ws, const float* __restrict__ Wf,
    const float* __restrict__ Ww, const float* __restrict__ Wt,
    const float* __restrict__ Wg, const float* __restrict__ Wfu,
    const float* __restrict__ Wdf, unsigned short* __restrict__ ws)
{
    int s = blockIdx.x * 256 + threadIdx.x;   // 0..20479 frag-lane slots
    const float* src; int K, N; unsigned base, S; int fi;
    if (s < 2048)      { src = Ws;            K = 64;  N = 256; base = WD0_B; S = 16384; fi = s; }
    else if (s < 4096) { src = Wf;            K = 64;  N = 256; base = WD1_B; S = 16384; fi = s - 2048; }
    else if (s < 6144) { src = Ww;            K = 64;  N = 256; base = WD2_B; S = 16384; fi = s - 4096; }
    else if (s < 10240){ src = Wt;            K = 256; N = 128; base = WT_B;  S = 32768; fi = s - 6144; }
    else if (s < 12288){ src = Wg;            K = 128; N = 128; base = WG_B;  S = 16384; fi = s - 10240; }
    else if (s < 14336){ src = Wfu;           K = 128; N = 128; base = WF0_B; S = 16384; fi = s - 12288; }
    else if (s < 16384){ src = Wfu + 16384;   K = 128; N = 128; base = WF1_B; S = 16384; fi = s - 14336; }
    else if (s < 18432){ src = Wfu + 32768;   K = 128; N = 128; base = WF2_B; S = 16384; fi = s - 16384; }
    else               { src = Wdf;           K = 128; N = 128; base = WDF_B; S = 16384; fi = s - 18432; }
    const int lane = fi & 63, frag = fi >> 6;
    const int KC = K >> 5;
    const int nt = frag / KC, kc = frag - nt * KC;
    const int n  = nt * 16 + (lane & 15);
    const int k0 = kc * 32 + (lane >> 4) * 8;
    short8 hv, lv;
    #pragma unroll
    for (int j = 0; j < 8; ++j) {
        unsigned short h, l;
        split2(src[(k0 + j) * N + n], h, l);
        hv[j] = (short)h; lv[j] = (short)l;
    }
    *(short8*)&ws[base + (unsigned)fi * 8]     = hv;
    *(short8*)&ws[base + S + (unsigned)fi * 8] = lv;
}

// K=128 phase: acc[2] over both m-tiles. ALL 4 B pairs upfront. Each
// m-tile accumulates in 3 INDEPENDENT chains (hi=Ah*Bh, la=Al*Bh,
// lb=Ah*Bl) -> 6 chains, each touched once per kc: dependency distance 6
// instructions (~30cyc) > MFMA latency (~16cyc) -> fully pipelined issue.
// Combined with two exact f32 adds at the end (reassociation ~2^-24).
__device__ __forceinline__ void gemm128_d2(
    const unsigned short* __restrict__ wsB, unsigned S,
    const unsigned short* __restrict__ Ph, const unsigned short* __restrict__ Pl,
    int tok0, int tok1, int quad, int wv, int lane, f32x4 acc[2])
{
    short8 Bh[4], Bl[4];
    #pragma unroll
    for (int j = 0; j < 4; ++j) {
        const unsigned short* bp = wsB + ((unsigned)(wv * 4 + j) * 64 + lane) * 8;
        Bh[j] = *(const short8*)bp; Bl[j] = *(const short8*)(bp + S);
    }
    f32x4 h0 = acc[0], h1 = acc[1];
    f32x4 la0 = (f32x4){0.f, 0.f, 0.f, 0.f};
    f32x4 la1 = la0, lb0 = la0, lb1 = la0;
    #pragma unroll
    for (int kc = 0; kc < 4; ++kc) {
        const int k = kc * 32 + quad * 8;
        const short8 Ah0 = *(const short8*)&Ph[tok0 * TP + k];
        const short8 Al0 = *(const short8*)&Pl[tok0 * TP + k];
        const short8 Ah1 = *(const short8*)&Ph[tok1 * TP + k];
        const short8 Al1 = *(const short8*)&Pl[tok1 * TP + k];
        h0  = MFMA(Ah0, Bh[kc], h0);
        h1  = MFMA(Ah1, Bh[kc], h1);
        la0 = MFMA(Al0, Bh[kc], la0);
        la1 = MFMA(Al1, Bh[kc], la1);
        lb0 = MFMA(Ah0, Bl[kc], lb0);
        lb1 = MFMA(Ah1, Bl[kc], lb1);
    }
    acc[0] = (h0 + la0) + lb0;
    acc[1] = (h1 + la1) + lb1;
}

__global__ __launch_bounds__(512) void mega_kernel(
    const float* __restrict__ x0, const float* __restrict__ x1,
    const float* __restrict__ x2,
    const float* __restrict__ bd0, const float* __restrict__ bd1,
    const float* __restrict__ bd2,
    const float* __restrict__ g1, const float* __restrict__ b1,
    const float* __restrict__ bt, const float* __restrict__ Wg,
    const float* __restrict__ bg, const float* __restrict__ bfu,
    const float* __restrict__ bdf, const float* __restrict__ g2,
    const float* __restrict__ b2,
    const unsigned short* __restrict__ ws,
    float* __restrict__ out, float* __restrict__ consts,
    float* __restrict__ e0, float* __restrict__ e1, float* __restrict__ e2)
{
    // 54272 B carve with aliasing (2 blocks/CU):
    //   [0,17408):      xh/xl[32*72] UNION th/tl[32*136] (x -> t -> fused)
    //   [17408,51200):  ah/al[32*264] UNION eh/el[32*136] UNION ostage
    //   [51200,54272):  psumS[32][PP], psumQ[32][PP]
    __shared__ __align__(16) unsigned char smem[54272];
    unsigned short* xh = (unsigned short*)smem;            // [32][XP]
    unsigned short* xl = xh + 32 * XP;
    unsigned short* th = (unsigned short*)smem;            // [32][TP]
    unsigned short* tl = th + 32 * TP;
    unsigned short* ah = (unsigned short*)(smem + 17408);  // [32][AP]
    unsigned short* al = ah + 32 * AP;
    unsigned short* eh = (unsigned short*)(smem + 17408);  // [32][TP] enh planes
    unsigned short* el = eh + 32 * TP;
    float* ostage = (float*)(smem + 17408);                // aliases ah/eh (dead at epilogue)
    float* psumS  = (float*)(smem + 51200);                // [32][PP]
    float* psumQ  = psumS + 32 * PP;                       // [32][PP]

    const int tid = threadIdx.x, wv = tid >> 6, lane = tid & 63;
    const int lm = lane & 15, quad = lane >> 4;
    const int row0 = blockIdx.x * NTOK;
    const int tok0 = lm, tok1 = lm + 16;
    const int stok = tid >> 4, sc4 = (tid & 15) * 4;   // x-staging coords

    if (blockIdx.x == 0) {
        if (tid < 72) consts[tid] = 4.8828125e-4f;      // corr = 1/2048
        else if (tid < 96) consts[tid] = 0.125f;        // dw = 1/8
    }

    // columns: phase A -> 2 ntiles/wave (32 cols); 128-col phases -> 1 ntile
    int cA[2]; float g1c[2], b1c[2];
    #pragma unroll
    for (int i = 0; i < 2; ++i) { cA[i] = (wv * 2 + i) * 16 + lm; g1c[i] = g1[cA[i]]; b1c[i] = b1[cA[i]]; }
    const int cT = wv * 16 + lm;
    const float btc = bt[cT];
    const float bgc = bg[cT] + 4.8828125e-4f * (Wg[16384 + cT] + Wg[16512 + cT] + Wg[16640 + cT]);
    const float bdc = bdf[cT], g2c = g2[cT], b2c = b2[cT];
    f32x4 facc[2];
    { const float bv = bfu[cT]; facc[0] = (f32x4){bv, bv, bv, bv}; facc[1] = facc[0]; }

    const float* xs[3]  = {x0, x1, x2};
    const float* bds[3] = {bd0, bd1, bd2};
    float* es[3] = {e0, e1, e2};
    const unsigned WDB[3] = {WD0_B, WD1_B, WD2_B};
    const unsigned WFB[3] = {WF0_B, WF1_B, WF2_B};

    // ---- pre-loop: stage x for d=0 ----
    {
        const f32x4 v = __builtin_nontemporal_load(
            (const f32x4*)&xs[0][(row0 + stok) * 64 + sc4]);
        stage_x(v, xh, xl, stok, sc4);
    }
    ldsbar();                               // B_a: x(0) planes ready

    for (int d = 0; d < 3; ++d) {
        // ---- Phase A: a_raw = x @ Wd + bd. 2 ntiles x 2 m, all-4 B upfront ----
        f32x4 acc[2][2];                    // [ntile i][mtile m]
        {
            const float* bdp = bds[d];
            #pragma unroll
            for (int i = 0; i < 2; ++i) {
                const float bv = bdp[cA[i]];
                acc[i][0] = (f32x4){bv, bv, bv, bv}; acc[i][1] = acc[i][0];
            }
        }
        {
            short8 Bh[4], Bl[4];            // f = kc*2 + i; frag = (wv*2+i)*2+kc
            #pragma unroll
            for (int f = 0; f < 4; ++f) {
                const int kc = f >> 1, i = f & 1;
                const unsigned short* bp = ws + WDB[d] +
                    ((unsigned)((wv * 2 + i) * 2 + kc) * 64 + lane) * 8;
                Bh[f] = *(const short8*)bp; Bl[f] = *(const short8*)(bp + 16384);
            }
            #pragma unroll
            for (int f = 0; f < 4; ++f) {   // f = kc*2 + i
                const int kc = f >> 1, i = f & 1;
                const int k = kc * 32 + quad * 8;
                const short8 Ah0 = *(const short8*)&xh[tok0 * XP + k];
                const short8 Al0 = *(const short8*)&xl[tok0 * XP + k];
                const short8 Ah1 = *(const short8*)&xh[tok1 * XP + k];
                const short8 Al1 = *(const short8*)&xl[tok1 * XP + k];
                acc[i][0] = MFMA(Ah0, Bh[f], acc[i][0]);
                acc[i][1] = MFMA(Ah1, Bh[f], acc[i][1]);
                acc[i][0] = MFMA(Al0, Bh[f], acc[i][0]);
                acc[i][1] = MFMA(Al1, Bh[f], acc[i][1]);
                acc[i][0] = MFMA(Ah0, Bl[f], acc[i][0]);
                acc[i][1] = MFMA(Ah1, Bl[f], acc[i][1]);
            }
        }
        // LN partials over this wave's 32 cols
        #pragma unroll
        for (int m = 0; m < 2; ++m)
            #pragma unroll
            for (int r = 0; r < 4; ++r) {
                float s = acc[0][m][r] + acc[1][m][r];
                float q = acc[0][m][r] * acc[0][m][r] + acc[1][m][r] * acc[1][m][r];
                #pragma unroll
                for (int off = 1; off < 16; off <<= 1) {
                    s += __shfl_xor(s, off); q += __shfl_xor(q, off);
                }
                if (lm == 0) {
                    const int row = m * 16 + quad * 4 + r;
                    psumS[row * PP + wv] = s;
                    psumQ[row * PP + wv] = q;
                }
            }
        ldsbar();                           // B_b: psum ready (also: all x reads done)

        // normalize + a-planes store (ah/al)
        #pragma unroll
        for (int m = 0; m < 2; ++m)
            #pragma unroll
            for (int r = 0; r < 4; ++r) {
                const int row = m * 16 + quad * 4 + r;
                const float4 s0 = *(const float4*)&psumS[row * PP];
                const float4 s1 = *(const float4*)&psumS[row * PP + 4];
                const float4 q0 = *(const float4*)&psumQ[row * PP];
                const float4 q1 = *(const float4*)&psumQ[row * PP + 4];
                const float S = s0.x + s0.y + s0.z + s0.w + s1.x + s1.y + s1.z + s1.w;
                const float Q = q0.x + q0.y + q0.z + q0.w + q1.x + q1.y + q1.z + q1.w;
                const float mean = S * (1.f / 256.f);
                const float rs = rsqrtf(Q * (1.f / 256.f) - mean * mean + 1e-3f);
                const float v0 = (acc[0][m][r] - mean) * rs * g1c[0] + b1c[0];
                const float v1 = (acc[1][m][r] - mean) * rs * g1c[1] + b1c[1];
                unsigned hp, lp; split2pk(v0, v1, hp, lp);
                ah[row * AP + cA[0]] = (unsigned short)hp;
                ah[row * AP + cA[1]] = (unsigned short)(hp >> 16);
                al[row * AP + cA[0]] = (unsigned short)lp;
                al[row * AP + cA[1]] = (unsigned short)(lp >> 16);
            }
        ldsbar();                           // B_c: a planes ready

        // prefetch next domain's x into regs (used at tail — latency hidden;
        // stays in flight across B_d/B_e with lgkm-only barriers)
        f32x4 xvn;
        if (d < 2)
            xvn = __builtin_nontemporal_load(
                (const f32x4*)&xs[d + 1][(row0 + stok) * 64 + sc4]);

        // ---- Phase T: t = a @ Wt + bt. 8 kc, depth-4 B roll, 6 chains ----
        f32x4 tac[2];
        {
            f32x4 h0 = (f32x4){btc, btc, btc, btc}, h1 = h0;
            f32x4 la0 = (f32x4){0.f, 0.f, 0.f, 0.f};
            f32x4 la1 = la0, lb0 = la0, lb1 = la0;
            short8 Bh[4], Bl[4];
            #pragma unroll
            for (int j = 0; j < 4; ++j) {
                const unsigned short* bp = ws + WT_B + ((unsigned)(wv * 8 + j) * 64 + lane) * 8;
                Bh[j] = *(const short8*)bp; Bl[j] = *(const short8*)(bp + 32768);
            }
            #pragma unroll
            for (int kc = 0; kc < 8; ++kc) {
                const short8 bh = Bh[kc & 3], bl = Bl[kc & 3];
                if (kc + 4 < 8) {
                    const unsigned short* bp = ws + WT_B + ((unsigned)(wv * 8 + kc + 4) * 64 + lane) * 8;
                    Bh[kc & 3] = *(const short8*)bp; Bl[kc & 3] = *(const short8*)(bp + 32768);
                }
                const int k = kc * 32 + quad * 8;
                const short8 Ah0 = *(const short8*)&ah[tok0 * AP + k];
                const short8 Al0 = *(const short8*)&al[tok0 * AP + k];
                const short8 Ah1 = *(const short8*)&ah[tok1 * AP + k];
                const short8 Al1 = *(const short8*)&al[tok1 * AP + k];
                h0  = MFMA(Ah0, bh, h0);
                h1  = MFMA(Ah1, bh, h1);
                la0 = MFMA(Al0, bh, la0);
                la1 = MFMA(Al1, bh, la1);
                lb0 = MFMA(Ah0, bl, lb0);
                lb1 = MFMA(Ah1, bl, lb1);
            }
            tac[0] = (h0 + la0) + lb0;
            tac[1] = (h1 + la1) + lb1;
        }
        // t -> th/tl (x region: all x reads done at B_b; safe to overwrite)
        #pragma unroll
        for (int m = 0; m < 2; ++m) {
            const int rb = m * 16 + quad * 4;
            unsigned hp, lp;
            split2pk(tac[m][0], tac[m][1], hp, lp);
            th[rb * TP + cT]       = (unsigned short)hp;
            th[(rb + 1) * TP + cT] = (unsigned short)(hp >> 16);
            tl[rb * TP + cT]       = (unsigned short)lp;
            tl[(rb + 1) * TP + cT] = (unsigned short)(lp >> 16);
            split2pk(tac[m][2], tac[m][3], hp, lp);
            th[(rb + 2) * TP + cT] = (unsigned short)hp;
            th[(rb + 3) * TP + cT] = (unsigned short)(hp >> 16);
            tl[(rb + 2) * TP + cT] = (unsigned short)lp;
            tl[(rb + 3) * TP + cT] = (unsigned short)(lp >> 16);
        }
        ldsbar();                           // B_d: t planes ready (also: all a reads done)

        // ---- Phase G: z = t @ Wg0 + bg_eff ----
        f32x4 zac[2];
        zac[0] = (f32x4){bgc, bgc, bgc, bgc}; zac[1] = zac[0];
        gemm128_d2(ws + WG_B, 16384, th, tl, tok0, tok1, quad, wv, lane, zac);

        // enh = t * sigmoid(z)/8 -> eh/el (a region: free after B_d)
        #pragma unroll
        for (int m = 0; m < 2; ++m) {
            const int rb = m * 16 + quad * 4;
            float e[4];
            #pragma unroll
            for (int r = 0; r < 4; ++r) {
                const int row = rb + r;
                const float tv = bf2f(th[row * TP + cT]) + bf2f(tl[row * TP + cT]);
                e[r] = tv * (1.f / (1.f + __expf(-zac[m][r]))) * 0.125f;
            }
            unsigned hp, lp;
            split2pk(e[0], e[1], hp, lp);
            eh[rb * TP + cT]       = (unsigned short)hp;
            eh[(rb + 1) * TP + cT] = (unsigned short)(hp >> 16);
            el[rb * TP + cT]       = (unsigned short)lp;
            el[(rb + 1) * TP + cT] = (unsigned short)(lp >> 16);
            split2pk(e[2], e[3], hp, lp);
            eh[(rb + 2) * TP + cT] = (unsigned short)hp;
            eh[(rb + 3) * TP + cT] = (unsigned short)(hp >> 16);
            el[(rb + 2) * TP + cT] = (unsigned short)lp;
            el[(rb + 3) * TP + cT] = (unsigned short)(lp >> 16);
        }
        ldsbar();                           // B_e: enh planes ready (also: all t/G reads done)

        // ---- Fuse acc: facc += enh_d @ Wfu_d (reads eh/el) ----
        gemm128_d2(ws + WFB[d], 16384, eh, el, tok0, tok1, quad, wv, lane, facc);

        // enh global store: full 512B rows, nontemporal (ack never waited)
        #pragma unroll
        for (int p = 0; p < 2; ++p) {
            const int row = (tid >> 5) + p * 16;
            const int c4 = (tid & 31) * 4;
            const ushort4 h0 = *(const ushort4*)&eh[row * TP + c4];
            const ushort4 l0 = *(const ushort4*)&el[row * TP + c4];
            f32x4 o = {bf2f(h0.x) + bf2f(l0.x), bf2f(h0.y) + bf2f(l0.y),
                       bf2f(h0.z) + bf2f(l0.z), bf2f(h0.w) + bf2f(l0.w)};
            __builtin_nontemporal_store(o, (f32x4*)(es[d] + (row0 + row) * 128 + c4));
        }

        // tail store into th/tl (free after B_e): x(d+1) or fused planes
        if (d < 2) {
            stage_x(xvn, xh, xl, stok, sc4);
        } else {
            #pragma unroll
            for (int m = 0; m < 2; ++m) {
                const int rb = m * 16 + quad * 4;
                unsigned hp, lp;
                split2pk(facc[m][0], facc[m][1], hp, lp);
                th[rb * TP + cT]       = (unsigned short)hp;
                th[(rb + 1) * TP + cT] = (unsigned short)(hp >> 16);
                tl[rb * TP + cT]       = (unsigned short)lp;
                tl[(rb + 1) * TP + cT] = (unsigned short)(lp >> 16);
                split2pk(facc[m][2], facc[m][3], hp, lp);
                th[(rb + 2) * TP + cT] = (unsigned short)hp;
                th[(rb + 3) * TP + cT] = (unsigned short)(hp >> 16);
                tl[(rb + 2) * TP + cT] = (unsigned short)lp;
                tl[(rb + 3) * TP + cT] = (unsigned short)(lp >> 16);
            }
        }
        ldsbar();                           // B_f: th/tl ready for next phase
    }

    // ---- df = fused @ Wdf + bdf (reads th/tl) ----
    f32x4 dac[2];
    dac[0] = (f32x4){bdc, bdc, bdc, bdc}; dac[1] = dac[0];
    gemm128_d2(ws + WDF_B, 16384, th, tl, tok0, tok1, quad, wv, lane, dac);

    // ---- final LN over 128 (wave partial = its 16 cols) ----
    #pragma unroll
    for (int m = 0; m < 2; ++m)
        #pragma unroll
        for (int r = 0; r < 4; ++r) {
            float s = dac[m][r];
            float q = dac[m][r] * dac[m][r];
            #pragma unroll
            for (int off = 1; off < 16; off <<= 1) {
                s += __shfl_xor(s, off); q += __shfl_xor(q, off);
            }
            if (lm == 0) {
                const int row = m * 16 + quad * 4 + r;
                psumS[row * PP + wv] = s;
                psumQ[row * PP + wv] = q;
            }
        }
    ldsbar();
    #pragma unroll
    for (int m = 0; m < 2; ++m)
        #pragma unroll
        for (int r = 0; r < 4; ++r) {
            const int row = m * 16 + quad * 4 + r;
            const float4 s0 = *(const float4*)&psumS[row * PP];
            const float4 s1 = *(const float4*)&psumS[row * PP + 4];
            const float4 q0 = *(const float4*)&psumQ[row * PP];
            const float4 q1 = *(const float4*)&psumQ[row * PP + 4];
            const float S = s0.x + s0.y + s0.z + s0.w + s1.x + s1.y + s1.z + s1.w;
            const float Q = q0.x + q0.y + q0.z + q0.w + q1.x + q1.y + q1.z + q1.w;
            const float mean = S * (1.f / 128.f);
            const float rs = rsqrtf(Q * (1.f / 128.f) - mean * mean + 1e-3f);
            ostage[row * 128 + cT] = (dac[m][r] - mean) * rs * g2c + b2c;
        }
    ldsbar();
    // out store: full lines
    #pragma unroll
    for (int p = 0; p < 2; ++p) {
        const int row = (tid >> 5) + p * 16;
        const int c4 = (tid & 31) * 4;
        const f32x4 o = *(const f32x4*)&ostage[row * 128 + c4];
        __builtin_nontemporal_store(o, (f32x4*)(out + (row0 + row) * 128 + c4));
    }
}

extern "C" void kernel_launch(void* const* d_in, const int* in_sizes, int n_in,
                              void* d_out, int out_size, void* d_ws, size_t ws_size,
                              hipStream_t stream) {
    const float* spatial   = (const float*)d_in[0];
    const float* frequency = (const float*)d_in[1];
    const float* wavelet   = (const float*)d_in[2];
    const float* Ws  = (const float*)d_in[3];
    const float* bs  = (const float*)d_in[4];
    const float* Wf  = (const float*)d_in[5];
    const float* bf  = (const float*)d_in[6];
    const float* Ww  = (const float*)d_in[7];
    const float* bw  = (const float*)d_in[8];
    const float* g1  = (const float*)d_in[9];
    const float* b1  = (const float*)d_in[10];
    // d_in[11..14] = Wk, bk, Wq, bq — provably unused (corr is constant)
    const float* Wt  = (const float*)d_in[15];
    const float* bt  = (const float*)d_in[16];
    const float* Wg  = (const float*)d_in[17];
    const float* bg  = (const float*)d_in[18];
    const float* Wfu = (const float*)d_in[19];
    const float* bfu = (const float*)d_in[20];
    const float* Wdf = (const float*)d_in[21];
    const float* bdf = (const float*)d_in[22];
    const float* g2  = (const float*)d_in[23];
    const float* b2  = (const float*)d_in[24];

    float* out    = (float*)d_out;
    float* consts = out + 2097152;          // corr[72] + dw[24]
    float* enh0   = out + 2097248;
    float* enh1   = out + 4194400;
    float* enh2   = out + 6291552;
    unsigned short* wsp = (unsigned short*)d_ws;   // needs 655360 B

    prep_kernel<<<80, 256, 0, stream>>>(Ws, Wf, Ww, Wt, Wg, Wfu, Wdf, wsp);
    mega_kernel<<<16384 / NTOK, 512, 0, stream>>>(
        spatial, frequency, wavelet, bs, bf, bw, g1, b1,
        bt, Wg, bg, bfu, bdf, g2, b2, wsp,
        out, consts, enh0, enh1, enh2);
}